// Round 13
// baseline (394.180 us; speedup 1.0000x reference)
//
#include <hip/hip_runtime.h>
#include <hip/hip_fp16.h>

typedef _Float16 v2h __attribute__((ext_vector_type(2)));
typedef _Float16 h4t __attribute__((ext_vector_type(4)));
typedef _Float16 h8t __attribute__((ext_vector_type(8)));
typedef float f4t __attribute__((ext_vector_type(4)));

static constexpr int T = 512;
static constexpr int B = 4096;

__device__ __forceinline__ float frcp_(float x) { return __builtin_amdgcn_rcpf(x); }
__device__ __forceinline__ float sig_(float x) { return frcp_(1.0f + __expf(-x)); }
__device__ __forceinline__ float tanh_(float x) { return 1.0f - 2.0f * frcp_(1.0f + __expf(2.0f * x)); }

// Compiler fence + scheduling barrier (same-wave LDS ops are in-order in HW).
#define WAVE_SYNC() do { asm volatile("" ::: "memory"); \
                         __builtin_amdgcn_wave_barrier(); \
                         asm volatile("" ::: "memory"); } while (0)

__device__ __forceinline__ v2h as_h2_(unsigned u) {
    union { unsigned u; v2h h; } c; c.u = u; return c.h;
}

// pack 4 floats -> h4t via two v_cvt_pkrtz
__device__ __forceinline__ h4t pack4_(float a, float b, float c, float d) {
    auto p0 = __builtin_amdgcn_cvt_pkrtz(a, b);   // __fp16 x2
    auto p1 = __builtin_amdgcn_cvt_pkrtz(c, d);
    union { struct { decltype(p0) a, b; } p; h4t h; } cv;
    cv.p.a = p0; cv.p.b = p1;
    return cv.h;
}

// ---------------- Kernel 1: layer-0 forward AND backward scans -------------
// (unchanged from round 12 — proven 149 us)
__global__ void __launch_bounds__(256, 2) k_l0(
    const float* __restrict__ x,      // [B,T]
    const float* __restrict__ Wf, const float* __restrict__ Uf,
    const float* __restrict__ bif, const float* __restrict__ bhf,
    const float* __restrict__ Wb, const float* __restrict__ Ub,
    const float* __restrict__ bib, const float* __restrict__ bhb,
    __half* __restrict__ y0f,         // [T,B,16] f16
    __half* __restrict__ y0b)         // [T,B,16] f16
{
    __shared__ __half hbuf[256];      // 16 units x 16 f16 (32 B/unit)
    const int tid  = threadIdx.x;
    const int j    = tid & 15;
    const int dir  = (tid >> 4) & 1;
    const int s    = tid >> 5;
    const int unit = tid >> 4;
    const int b    = blockIdx.x * 8 + s;
    __half* hb = hbuf + unit * 16;

    const float* Wih = dir ? Wb : Wf;
    const float* Whh = dir ? Ub : Uf;
    const float* bih = dir ? bib : bif;
    const float* bhh = dir ? bhb : bhf;

    v2h wr[8], wz[8], wn[8];
#pragma unroll
    for (int q = 0; q < 8; ++q) {
        wr[q] = (v2h){ (_Float16)Whh[j * 16 + 2 * q],
                       (_Float16)Whh[j * 16 + 2 * q + 1] };
        wz[q] = (v2h){ (_Float16)Whh[(16 + j) * 16 + 2 * q],
                       (_Float16)Whh[(16 + j) * 16 + 2 * q + 1] };
        wn[q] = (v2h){ (_Float16)Whh[(32 + j) * 16 + 2 * q],
                       (_Float16)Whh[(32 + j) * 16 + 2 * q + 1] };
    }
    const float wxr  = Wih[j], wxz = Wih[16 + j], wxn = Wih[32 + j];
    const float br   = bih[j] + bhh[j];
    const float bz   = bih[16 + j] + bhh[16 + j];
    const float bin_ = bih[32 + j];
    const float bhn  = bhh[32 + j];

    const int t0   = dir ? (T - 1) : 0;
    const int step = dir ? -1 : 1;
    const float* xp = x + (size_t)b * T + t0;
    __half* yp = (dir ? y0b : y0f) + ((size_t)t0 * B + b) * 16 + j;
    const ptrdiff_t ystep = (ptrdiff_t)step * B * 16;

    hb[j] = __half(0.0f);
    WAVE_SYNC();

    float xv = xp[0];
    float x1 = xp[step];
    const float* xq = xp + 2 * step;   // 2-deep prefetch
    float hj = 0.0f;

    for (int it = 0; it < T; ++it) {
        float x2 = *xq;
        if (it < T - 3) xq += step;
        const uint4* hp = reinterpret_cast<const uint4*>(hb);
        uint4 u0 = hp[0], u1 = hp[1];
        const unsigned hw[8] = { u0.x, u0.y, u0.z, u0.w, u1.x, u1.y, u1.z, u1.w };
        float ar = fmaf(xv, wxr, br);
        float az = fmaf(xv, wxz, bz);
        float hn = bhn;
#pragma unroll
        for (int q = 0; q < 8; ++q) {
            v2h hh = as_h2_(hw[q]);
            ar = __builtin_amdgcn_fdot2(hh, wr[q], ar, false);
            az = __builtin_amdgcn_fdot2(hh, wz[q], az, false);
            hn = __builtin_amdgcn_fdot2(hh, wn[q], hn, false);
        }
        float r = sig_(ar), z = sig_(az);
        float n = tanh_(fmaf(r, hn, fmaf(xv, wxn, bin_)));
        hj = fmaf(z, hj - n, n);            // (1-z)*n + z*h
        __half hf = __float2half(hj);
        *yp = hf;
        yp += ystep;
        WAVE_SYNC();
        hb[j] = hf;
        WAVE_SYNC();
        xv = x1; x1 = x2;
    }
}

// ---------------- Kernel 2: layer-1 via MFMA, 2 x 16 sequences per wave ----
// Two independent 16-seq MFMA streams per wave (b0, b0+16) share weight
// fragments; their MFMA->nonlin->pack chains interleave to fill the
// latency that left the machine 97% idle at 1 stream (r12 profile).
__global__ void __launch_bounds__(64, 1) k_l1m(
    const __half* __restrict__ y0f, const __half* __restrict__ y0b,
    const float* __restrict__ Wih1, const float* __restrict__ Whh1,
    const float* __restrict__ bih1, const float* __restrict__ bhh1,
    const float* __restrict__ Wih1b,
    const float* __restrict__ bih1b, const float* __restrict__ bhh1b,
    float* __restrict__ out)              // [B,32]
{
    const int lane = threadIdx.x & 63;
    const int c = lane & 15;
    const int g = lane >> 4;
    const int b0 = blockIdx.x * 32 + c;
    const int b1 = b0 + 16;

    // shared A fragments
    h8t Air, Aiz, Ain;
    {
        const float* pr = Wih1 + (size_t)c * 32 + 8 * g;
        const float* pz = Wih1 + (size_t)(16 + c) * 32 + 8 * g;
        const float* pn = Wih1 + (size_t)(32 + c) * 32 + 8 * g;
#pragma unroll
        for (int e = 0; e < 8; ++e) {
            Air[e] = (_Float16)pr[e];
            Aiz[e] = (_Float16)pz[e];
            Ain[e] = (_Float16)pn[e];
        }
    }
    h4t Ahr, Ahz, Ahn;
    {
        const float* pr = Whh1 + (size_t)c * 16 + 4 * g;
        const float* pz = Whh1 + (size_t)(16 + c) * 16 + 4 * g;
        const float* pn = Whh1 + (size_t)(32 + c) * 16 + 4 * g;
#pragma unroll
        for (int e = 0; e < 4; ++e) {
            Ahr[e] = (_Float16)pr[e];
            Ahz[e] = (_Float16)pz[e];
            Ahn[e] = (_Float16)pn[e];
        }
    }
    f4t Crb, Czb, Cnb, Chn, Z4;
#pragma unroll
    for (int i = 0; i < 4; ++i) {
        const int row = 4 * g + i;
        Crb[i] = bih1[row] + bhh1[row];
        Czb[i] = bih1[16 + row] + bhh1[16 + row];
        Cnb[i] = bih1[32 + row];
        Chn[i] = bhh1[32 + row];
        Z4[i]  = 0.0f;
    }

    const __half* ysrc = (g < 2) ? y0f : y0b;
    const uint4* yp0 = reinterpret_cast<const uint4*>(
        ysrc + (size_t)b0 * 16 + (size_t)(g & 1) * 8);
    const uint4* yp1 = reinterpret_cast<const uint4*>(
        ysrc + (size_t)b1 * 16 + (size_t)(g & 1) * 8);
    const size_t ystr = (size_t)B * 2;            // uint4 per time step

    // 4-deep rotating prefetch per stream (static indices via unroll-4)
    uint4 buf0[4], buf1[4];
#pragma unroll
    for (int i = 0; i < 4; ++i) {
        buf0[i] = yp0[(size_t)i * ystr];
        buf1[i] = yp1[(size_t)i * ystr];
    }

    float h0[4] = {0.0f, 0.0f, 0.0f, 0.0f};
    float h1[4] = {0.0f, 0.0f, 0.0f, 0.0f};
    h4t Bh0 = {}, Bh1 = {};

    for (int ito = 0; ito < T / 4; ++ito) {
#pragma unroll
        for (int u = 0; u < 4; ++u) {
            const int it = ito * 4 + u;
            uint4 ya0 = buf0[u], ya1 = buf1[u];
            const size_t tn = (it + 4 < T) ? (size_t)(it + 4) : (size_t)(T - 1);
            buf0[u] = yp0[tn * ystr];
            buf1[u] = yp1[tn * ystr];
            h8t By0, By1;
            { union { uint4 u; h8t h; } cv; cv.u = ya0; By0 = cv.h; }
            { union { uint4 u; h8t h; } cv; cv.u = ya1; By1 = cv.h; }
            f4t Dr0 = __builtin_amdgcn_mfma_f32_16x16x32_f16(Air, By0, Crb, 0, 0, 0);
            f4t Dr1 = __builtin_amdgcn_mfma_f32_16x16x32_f16(Air, By1, Crb, 0, 0, 0);
            f4t Dz0 = __builtin_amdgcn_mfma_f32_16x16x32_f16(Aiz, By0, Czb, 0, 0, 0);
            f4t Dz1 = __builtin_amdgcn_mfma_f32_16x16x32_f16(Aiz, By1, Czb, 0, 0, 0);
            f4t Dn0 = __builtin_amdgcn_mfma_f32_16x16x32_f16(Ain, By0, Cnb, 0, 0, 0);
            f4t Dn1 = __builtin_amdgcn_mfma_f32_16x16x32_f16(Ain, By1, Cnb, 0, 0, 0);
            f4t Er0 = __builtin_amdgcn_mfma_f32_16x16x16f16(Ahr, Bh0, Z4, 0, 0, 0);
            f4t Er1 = __builtin_amdgcn_mfma_f32_16x16x16f16(Ahr, Bh1, Z4, 0, 0, 0);
            f4t Ez0 = __builtin_amdgcn_mfma_f32_16x16x16f16(Ahz, Bh0, Z4, 0, 0, 0);
            f4t Ez1 = __builtin_amdgcn_mfma_f32_16x16x16f16(Ahz, Bh1, Z4, 0, 0, 0);
            f4t En0 = __builtin_amdgcn_mfma_f32_16x16x16f16(Ahn, Bh0, Chn, 0, 0, 0);
            f4t En1 = __builtin_amdgcn_mfma_f32_16x16x16f16(Ahn, Bh1, Chn, 0, 0, 0);
#pragma unroll
            for (int i = 0; i < 4; ++i) {
                float r0 = sig_(Dr0[i] + Er0[i]);
                float r1 = sig_(Dr1[i] + Er1[i]);
                float z0 = sig_(Dz0[i] + Ez0[i]);
                float z1 = sig_(Dz1[i] + Ez1[i]);
                float n0 = tanh_(fmaf(r0, En0[i], Dn0[i]));
                float n1 = tanh_(fmaf(r1, En1[i], Dn1[i]));
                h0[i] = fmaf(z0, h0[i] - n0, n0);
                h1[i] = fmaf(z1, h1[i] - n1, n1);
            }
            Bh0 = pack4_(h0[0], h0[1], h0[2], h0[3]);
            Bh1 = pack4_(h1[0], h1[1], h1[2], h1[3]);
        }
    }

#pragma unroll
    for (int i = 0; i < 4; ++i) {
        out[(size_t)b0 * 32 + 4 * g + i] = h0[i];
        out[(size_t)b1 * 32 + 4 * g + i] = h1[i];
    }

    // ---- L1 backward single step at t=T-1 from h=0 (both streams).
    // buf{0,1}[3] were refilled at it=T-1 with the clamped load y(T-1).
    uint4 yf0 = buf0[3], yf1 = buf1[3];
    h8t Abr, Abz, Abn;
    {
        const float* pr = Wih1b + (size_t)c * 32 + 8 * g;
        const float* pz = Wih1b + (size_t)(16 + c) * 32 + 8 * g;
        const float* pn = Wih1b + (size_t)(32 + c) * 32 + 8 * g;
#pragma unroll
        for (int e = 0; e < 8; ++e) {
            Abr[e] = (_Float16)pr[e];
            Abz[e] = (_Float16)pz[e];
            Abn[e] = (_Float16)pn[e];
        }
    }
    f4t Cbr, Cbz, Cbn;
    float ghn[4];
#pragma unroll
    for (int i = 0; i < 4; ++i) {
        const int row = 4 * g + i;
        Cbr[i] = bih1b[row] + bhh1b[row];
        Cbz[i] = bih1b[16 + row] + bhh1b[16 + row];
        Cbn[i] = bih1b[32 + row];
        ghn[i] = bhh1b[32 + row];
    }
    h8t Byf0, Byf1;
    { union { uint4 u; h8t h; } cv; cv.u = yf0; Byf0 = cv.h; }
    { union { uint4 u; h8t h; } cv; cv.u = yf1; Byf1 = cv.h; }
    f4t Dr0 = __builtin_amdgcn_mfma_f32_16x16x32_f16(Abr, Byf0, Cbr, 0, 0, 0);
    f4t Dr1 = __builtin_amdgcn_mfma_f32_16x16x32_f16(Abr, Byf1, Cbr, 0, 0, 0);
    f4t Dz0 = __builtin_amdgcn_mfma_f32_16x16x32_f16(Abz, Byf0, Cbz, 0, 0, 0);
    f4t Dz1 = __builtin_amdgcn_mfma_f32_16x16x32_f16(Abz, Byf1, Cbz, 0, 0, 0);
    f4t Dn0 = __builtin_amdgcn_mfma_f32_16x16x32_f16(Abn, Byf0, Cbn, 0, 0, 0);
    f4t Dn1 = __builtin_amdgcn_mfma_f32_16x16x32_f16(Abn, Byf1, Cbn, 0, 0, 0);
#pragma unroll
    for (int i = 0; i < 4; ++i) {
        float r0 = sig_(Dr0[i]), z0 = sig_(Dz0[i]);
        float n0 = tanh_(fmaf(r0, ghn[i], Dn0[i]));
        out[(size_t)b0 * 32 + 16 + 4 * g + i] = (1.0f - z0) * n0;
        float r1 = sig_(Dr1[i]), z1 = sig_(Dz1[i]);
        float n1 = tanh_(fmaf(r1, ghn[i], Dn1[i]));
        out[(size_t)b1 * 32 + 16 + 4 * g + i] = (1.0f - z1) * n1;
    }
}

extern "C" void kernel_launch(void* const* d_in, const int* in_sizes, int n_in,
                              void* d_out, int out_size, void* d_ws, size_t ws_size,
                              hipStream_t stream) {
    const float* x     = (const float*)d_in[0];
    const float* Wih0f = (const float*)d_in[1];
    const float* Whh0f = (const float*)d_in[2];
    const float* bih0f = (const float*)d_in[3];
    const float* bhh0f = (const float*)d_in[4];
    const float* Wih0b = (const float*)d_in[5];
    const float* Whh0b = (const float*)d_in[6];
    const float* bih0b = (const float*)d_in[7];
    const float* bhh0b = (const float*)d_in[8];
    const float* Wih1f = (const float*)d_in[9];
    const float* Whh1f = (const float*)d_in[10];
    const float* bih1f = (const float*)d_in[11];
    const float* bhh1f = (const float*)d_in[12];
    const float* Wih1b = (const float*)d_in[13];
    const float* bih1b = (const float*)d_in[15];
    const float* bhh1b = (const float*)d_in[16];

    __half* y0f = (__half*)d_ws;                   // [T,B,16] f16 = 64 MiB
    __half* y0b = y0f + (size_t)T * B * 16;        // [T,B,16] f16 = 64 MiB
    float* out = (float*)d_out;

    // K1: 8192 (seq,dir) units, 16 units/block -> 512 blocks.
    hipLaunchKernelGGL(k_l0, dim3(B * 2 / 16), dim3(256), 0, stream,
                       x, Wih0f, Whh0f, bih0f, bhh0f,
                       Wih0b, Whh0b, bih0b, bhh0b, y0f, y0b);
    // K2: 4096 seqs, 32 per wave (2 streams) -> 128 blocks.
    hipLaunchKernelGGL(k_l1m, dim3(B / 32), dim3(64), 0, stream,
                       y0f, y0b, Wih1f, Whh1f, bih1f, bhh1f,
                       Wih1b, bih1b, bhh1b, out);
}

// Round 14
// 250.372 us; speedup vs baseline: 1.5744x; 1.5744x over previous
//
#include <hip/hip_runtime.h>
#include <hip/hip_fp16.h>

typedef _Float16 v2h __attribute__((ext_vector_type(2)));
typedef _Float16 h4t __attribute__((ext_vector_type(4)));
typedef _Float16 h8t __attribute__((ext_vector_type(8)));
typedef float f4t __attribute__((ext_vector_type(4)));

static constexpr int T = 512;
static constexpr int B = 4096;

// prescale constants: sigmoid gates get -log2e, tanh gates get -2*log2e
static constexpr float SG = -1.4426950408889634f;
static constexpr float SN = -2.8853900817779268f;

__device__ __forceinline__ float frcp_(float x) { return __builtin_amdgcn_rcpf(x); }
__device__ __forceinline__ float exp2_(float x) {
#if __has_builtin(__builtin_amdgcn_exp2f)
    return __builtin_amdgcn_exp2f(x);
#else
    return __expf(x * 0.69314718055994531f);   // e^(x ln2) = 2^x
#endif
}
// with prescaled pre-activations: sig(y) = rcp(1+2^(-y*log2e)),
// tanh(y) = 2*rcp(1+2^(-2y*log2e)) - 1
__device__ __forceinline__ float sigp_(float p) { return frcp_(1.0f + exp2_(p)); }
__device__ __forceinline__ float tanhp_(float p) { return fmaf(2.0f, frcp_(1.0f + exp2_(p)), -1.0f); }

// Compiler fence + scheduling barrier (same-wave LDS ops are in-order in HW).
#define WAVE_SYNC() do { asm volatile("" ::: "memory"); \
                         __builtin_amdgcn_wave_barrier(); \
                         asm volatile("" ::: "memory"); } while (0)

__device__ __forceinline__ v2h as_h2_(unsigned u) {
    union { unsigned u; v2h h; } c; c.u = u; return c.h;
}

// pack 4 floats -> h4t via two v_cvt_pkrtz
__device__ __forceinline__ h4t pack4_(float a, float b, float c, float d) {
    auto p0 = __builtin_amdgcn_cvt_pkrtz(a, b);   // __fp16 x2
    auto p1 = __builtin_amdgcn_cvt_pkrtz(c, d);
    union { struct { decltype(p0) a, b; } p; h4t h; } cv;
    cv.p.a = p0; cv.p.b = p1;
    return cv.h;
}

// ---------------- Kernel 1: layer-0 forward AND backward scans -------------
// r12 structure (proven 149 us) + exp2 prefolding of gate weights/biases.
__global__ void __launch_bounds__(256, 2) k_l0(
    const float* __restrict__ x,      // [B,T]
    const float* __restrict__ Wf, const float* __restrict__ Uf,
    const float* __restrict__ bif, const float* __restrict__ bhf,
    const float* __restrict__ Wb, const float* __restrict__ Ub,
    const float* __restrict__ bib, const float* __restrict__ bhb,
    __half* __restrict__ y0f,         // [T,B,16] f16
    __half* __restrict__ y0b)         // [T,B,16] f16
{
    __shared__ __half hbuf[256];      // 16 units x 16 f16 (32 B/unit)
    const int tid  = threadIdx.x;
    const int j    = tid & 15;
    const int dir  = (tid >> 4) & 1;
    const int s    = tid >> 5;
    const int unit = tid >> 4;
    const int b    = blockIdx.x * 8 + s;
    __half* hb = hbuf + unit * 16;

    const float* Wih = dir ? Wb : Wf;
    const float* Whh = dir ? Ub : Uf;
    const float* bih = dir ? bib : bif;
    const float* bhh = dir ? bhb : bhf;

    // f16-packed hh weight rows, prescaled (r,z: SG; n: SN)
    v2h wr[8], wz[8], wn[8];
#pragma unroll
    for (int q = 0; q < 8; ++q) {
        wr[q] = (v2h){ (_Float16)(SG * Whh[j * 16 + 2 * q]),
                       (_Float16)(SG * Whh[j * 16 + 2 * q + 1]) };
        wz[q] = (v2h){ (_Float16)(SG * Whh[(16 + j) * 16 + 2 * q]),
                       (_Float16)(SG * Whh[(16 + j) * 16 + 2 * q + 1]) };
        wn[q] = (v2h){ (_Float16)(SN * Whh[(32 + j) * 16 + 2 * q]),
                       (_Float16)(SN * Whh[(32 + j) * 16 + 2 * q + 1]) };
    }
    const float wxr  = SG * Wih[j], wxz = SG * Wih[16 + j], wxn = SN * Wih[32 + j];
    const float br   = SG * (bih[j] + bhh[j]);
    const float bz   = SG * (bih[16 + j] + bhh[16 + j]);
    const float bin_ = SN * bih[32 + j];
    const float bhn  = SN * bhh[32 + j];

    const int t0   = dir ? (T - 1) : 0;
    const int step = dir ? -1 : 1;
    const float* xp = x + (size_t)b * T + t0;
    __half* yp = (dir ? y0b : y0f) + ((size_t)t0 * B + b) * 16 + j;
    const ptrdiff_t ystep = (ptrdiff_t)step * B * 16;

    hb[j] = __half(0.0f);
    WAVE_SYNC();

    float xv = xp[0];
    float x1 = xp[step];
    const float* xq = xp + 2 * step;   // 2-deep prefetch
    float hj = 0.0f;

    for (int it = 0; it < T; ++it) {
        float x2 = *xq;
        if (it < T - 3) xq += step;
        const uint4* hp = reinterpret_cast<const uint4*>(hb);
        uint4 u0 = hp[0], u1 = hp[1];
        float ar = fmaf(xv, wxr, br);
        float az = fmaf(xv, wxz, bz);
        float hn = bhn;
        {
            v2h hh;
            hh = as_h2_(u0.x);
            ar = __builtin_amdgcn_fdot2(hh, wr[0], ar, false);
            az = __builtin_amdgcn_fdot2(hh, wz[0], az, false);
            hn = __builtin_amdgcn_fdot2(hh, wn[0], hn, false);
            hh = as_h2_(u0.y);
            ar = __builtin_amdgcn_fdot2(hh, wr[1], ar, false);
            az = __builtin_amdgcn_fdot2(hh, wz[1], az, false);
            hn = __builtin_amdgcn_fdot2(hh, wn[1], hn, false);
            hh = as_h2_(u0.z);
            ar = __builtin_amdgcn_fdot2(hh, wr[2], ar, false);
            az = __builtin_amdgcn_fdot2(hh, wz[2], az, false);
            hn = __builtin_amdgcn_fdot2(hh, wn[2], hn, false);
            hh = as_h2_(u0.w);
            ar = __builtin_amdgcn_fdot2(hh, wr[3], ar, false);
            az = __builtin_amdgcn_fdot2(hh, wz[3], az, false);
            hn = __builtin_amdgcn_fdot2(hh, wn[3], hn, false);
            hh = as_h2_(u1.x);
            ar = __builtin_amdgcn_fdot2(hh, wr[4], ar, false);
            az = __builtin_amdgcn_fdot2(hh, wz[4], az, false);
            hn = __builtin_amdgcn_fdot2(hh, wn[4], hn, false);
            hh = as_h2_(u1.y);
            ar = __builtin_amdgcn_fdot2(hh, wr[5], ar, false);
            az = __builtin_amdgcn_fdot2(hh, wz[5], az, false);
            hn = __builtin_amdgcn_fdot2(hh, wn[5], hn, false);
            hh = as_h2_(u1.z);
            ar = __builtin_amdgcn_fdot2(hh, wr[6], ar, false);
            az = __builtin_amdgcn_fdot2(hh, wz[6], az, false);
            hn = __builtin_amdgcn_fdot2(hh, wn[6], hn, false);
            hh = as_h2_(u1.w);
            ar = __builtin_amdgcn_fdot2(hh, wr[7], ar, false);
            az = __builtin_amdgcn_fdot2(hh, wz[7], az, false);
            hn = __builtin_amdgcn_fdot2(hh, wn[7], hn, false);
        }
        float r = sigp_(ar), z = sigp_(az);
        float n = tanhp_(fmaf(r, hn, fmaf(xv, wxn, bin_)));
        hj = fmaf(z, hj - n, n);            // (1-z)*n + z*h
        __half hf = __float2half(hj);
        *yp = hf;
        yp += ystep;
        WAVE_SYNC();
        hb[j] = hf;
        WAVE_SYNC();
        xv = x1; x1 = x2;
    }
}

// ---------------- Kernel 2: layer-1 via MFMA, 16 sequences per wave --------
// r12 single-stream base + exp2 prefolding + C-chaining (ih-MFMA result is
// the C operand of the r/z hh-MFMA, deleting the D+E adds and letting the
// y-only ih-MFMAs issue before h is ready).
__global__ void __launch_bounds__(64, 1) k_l1m(
    const __half* __restrict__ y0f, const __half* __restrict__ y0b,
    const float* __restrict__ Wih1, const float* __restrict__ Whh1,
    const float* __restrict__ bih1, const float* __restrict__ bhh1,
    const float* __restrict__ Wih1b,
    const float* __restrict__ bih1b, const float* __restrict__ bhh1b,
    float* __restrict__ out)              // [B,32]
{
    const int lane = threadIdx.x & 63;
    const int c = lane & 15;
    const int g = lane >> 4;
    const int b = blockIdx.x * 16 + c;

    h8t Air, Aiz, Ain;
    {
        const float* pr = Wih1 + (size_t)c * 32 + 8 * g;
        const float* pz = Wih1 + (size_t)(16 + c) * 32 + 8 * g;
        const float* pn = Wih1 + (size_t)(32 + c) * 32 + 8 * g;
#pragma unroll
        for (int e = 0; e < 8; ++e) {
            Air[e] = (_Float16)(SG * pr[e]);
            Aiz[e] = (_Float16)(SG * pz[e]);
            Ain[e] = (_Float16)(SN * pn[e]);
        }
    }
    h4t Ahr, Ahz, Ahn;
    {
        const float* pr = Whh1 + (size_t)c * 16 + 4 * g;
        const float* pz = Whh1 + (size_t)(16 + c) * 16 + 4 * g;
        const float* pn = Whh1 + (size_t)(32 + c) * 16 + 4 * g;
#pragma unroll
        for (int e = 0; e < 4; ++e) {
            Ahr[e] = (_Float16)(SG * pr[e]);
            Ahz[e] = (_Float16)(SG * pz[e]);
            Ahn[e] = (_Float16)(SN * pn[e]);
        }
    }
    f4t Crb, Czb, Cnb, Chn;
#pragma unroll
    for (int i = 0; i < 4; ++i) {
        const int row = 4 * g + i;
        Crb[i] = SG * (bih1[row] + bhh1[row]);
        Czb[i] = SG * (bih1[16 + row] + bhh1[16 + row]);
        Cnb[i] = SN * bih1[32 + row];
        Chn[i] = SN * bhh1[32 + row];
    }

    const __half* ysrc = (g < 2) ? y0f : y0b;
    const uint4* yp = reinterpret_cast<const uint4*>(
        ysrc + (size_t)b * 16 + (size_t)(g & 1) * 8);
    const size_t ystr = (size_t)B * 2;            // uint4 per time step

    uint4 buf[8];
#pragma unroll
    for (int i = 0; i < 8; ++i) buf[i] = yp[(size_t)i * ystr];

    float h[4] = {0.0f, 0.0f, 0.0f, 0.0f};
    h4t Bh = {};

#pragma unroll 8
    for (int it = 0; it < T; ++it) {
        uint4 ya = buf[it & 7];
        const size_t tn = (it + 8 < T) ? (size_t)(it + 8) : (size_t)(T - 1);
        buf[it & 7] = yp[tn * ystr];              // issue load for t+8
        h8t By;
        { union { uint4 u; h8t h; } cv; cv.u = ya; By = cv.h; }
        f4t Dr = __builtin_amdgcn_mfma_f32_16x16x32_f16(Air, By, Crb, 0, 0, 0);
        f4t Dz = __builtin_amdgcn_mfma_f32_16x16x32_f16(Aiz, By, Czb, 0, 0, 0);
        f4t Dn = __builtin_amdgcn_mfma_f32_16x16x32_f16(Ain, By, Cnb, 0, 0, 0);
        f4t Er = __builtin_amdgcn_mfma_f32_16x16x16f16(Ahr, Bh, Dr, 0, 0, 0);  // C-chained
        f4t Ez = __builtin_amdgcn_mfma_f32_16x16x16f16(Ahz, Bh, Dz, 0, 0, 0);  // C-chained
        f4t En = __builtin_amdgcn_mfma_f32_16x16x16f16(Ahn, Bh, Chn, 0, 0, 0);
#pragma unroll
        for (int i = 0; i < 4; ++i) {
            float r = sigp_(Er[i]);
            float z = sigp_(Ez[i]);
            float n = tanhp_(fmaf(r, En[i], Dn[i]));
            h[i] = fmaf(z, h[i] - n, n);
        }
        Bh = pack4_(h[0], h[1], h[2], h[3]);
    }

#pragma unroll
    for (int i = 0; i < 4; ++i)
        out[(size_t)b * 32 + 4 * g + i] = h[i];

    // ---- L1 backward single step at t=T-1 from h=0.
    uint4 yfin = buf[(T - 1) & 7];
    h8t Abr, Abz, Abn;
    {
        const float* pr = Wih1b + (size_t)c * 32 + 8 * g;
        const float* pz = Wih1b + (size_t)(16 + c) * 32 + 8 * g;
        const float* pn = Wih1b + (size_t)(32 + c) * 32 + 8 * g;
#pragma unroll
        for (int e = 0; e < 8; ++e) {
            Abr[e] = (_Float16)(SG * pr[e]);
            Abz[e] = (_Float16)(SG * pz[e]);
            Abn[e] = (_Float16)(SN * pn[e]);
        }
    }
    f4t Cbr, Cbz, Cbn;
    float ghn[4];
#pragma unroll
    for (int i = 0; i < 4; ++i) {
        const int row = 4 * g + i;
        Cbr[i] = SG * (bih1b[row] + bhh1b[row]);
        Cbz[i] = SG * (bih1b[16 + row] + bhh1b[16 + row]);
        Cbn[i] = SN * bih1b[32 + row];
        ghn[i] = SN * bhh1b[32 + row];
    }
    h8t By;
    { union { uint4 u; h8t h; } cv; cv.u = yfin; By = cv.h; }
    f4t Dr = __builtin_amdgcn_mfma_f32_16x16x32_f16(Abr, By, Cbr, 0, 0, 0);
    f4t Dz = __builtin_amdgcn_mfma_f32_16x16x32_f16(Abz, By, Cbz, 0, 0, 0);
    f4t Dn = __builtin_amdgcn_mfma_f32_16x16x32_f16(Abn, By, Cbn, 0, 0, 0);
#pragma unroll
    for (int i = 0; i < 4; ++i) {
        float r = sigp_(Dr[i]);
        float z = sigp_(Dz[i]);
        float n = tanhp_(fmaf(r, ghn[i], Dn[i]));
        out[(size_t)b * 32 + 16 + 4 * g + i] = (1.0f - z) * n;
    }
}

extern "C" void kernel_launch(void* const* d_in, const int* in_sizes, int n_in,
                              void* d_out, int out_size, void* d_ws, size_t ws_size,
                              hipStream_t stream) {
    const float* x     = (const float*)d_in[0];
    const float* Wih0f = (const float*)d_in[1];
    const float* Whh0f = (const float*)d_in[2];
    const float* bih0f = (const float*)d_in[3];
    const float* bhh0f = (const float*)d_in[4];
    const float* Wih0b = (const float*)d_in[5];
    const float* Whh0b = (const float*)d_in[6];
    const float* bih0b = (const float*)d_in[7];
    const float* bhh0b = (const float*)d_in[8];
    const float* Wih1f = (const float*)d_in[9];
    const float* Whh1f = (const float*)d_in[10];
    const float* bih1f = (const float*)d_in[11];
    const float* bhh1f = (const float*)d_in[12];
    const float* Wih1b = (const float*)d_in[13];
    const float* bih1b = (const float*)d_in[15];
    const float* bhh1b = (const float*)d_in[16];

    __half* y0f = (__half*)d_ws;                   // [T,B,16] f16 = 64 MiB
    __half* y0b = y0f + (size_t)T * B * 16;        // [T,B,16] f16 = 64 MiB
    float* out = (float*)d_out;

    // K1: 8192 (seq,dir) units, 16 units/block -> 512 blocks.
    hipLaunchKernelGGL(k_l0, dim3(B * 2 / 16), dim3(256), 0, stream,
                       x, Wih0f, Whh0f, bih0f, bhh0f,
                       Wih0b, Whh0b, bih0b, bhh0b, y0f, y0b);
    // K2: 4096 seqs, 16 per wave -> 256 blocks.
    hipLaunchKernelGGL(k_l1m, dim3(B / 16), dim3(64), 0, stream,
                       y0f, y0b, Wih1f, Whh1f, bih1f, bhh1f,
                       Wih1b, bih1b, bhh1b, out);
}